// Round 3
// baseline (261.974 us; speedup 1.0000x reference)
//
#include <hip/hip_runtime.h>

#define HW_ 65536
#define W_ 1024
#define H_ 64
#define B_ 2
#define C_ 68
#define NPIX 131072
#define EPS 1e-5f

// ws float layout:
//   P1 [34][256] @ 0        (stats1 partials: 0-7 ta sum, 8-15 ta^2, 16-23 tg, 24-31 tg^2, 32 msel n, 33 center n)
//   P2 [16][256] @ 8704     (stats2 partials: 0-7 sum, 8-15 sum^2)
//   AT [256]     @ 12800    (abn atomic sums[128] + sumsq[128]; memset 0)
//   out_pre bf16 @ float 13312 (byte 53248), NPIX*64 elements

typedef __attribute__((ext_vector_type(8))) short short8;
typedef __attribute__((ext_vector_type(4))) float floatx4;

__device__ __forceinline__ unsigned short f2bf(float f) {
  unsigned u = __float_as_uint(f);
  u += 0x7fffu + ((u >> 16) & 1u);
  return (unsigned short)(u >> 16);
}
__device__ __forceinline__ unsigned pack2(float a, float b) {
  return (unsigned)f2bf(a) | ((unsigned)f2bf(b) << 16);
}
__device__ __forceinline__ float bf2f(unsigned short u) {
  return __uint_as_float(((unsigned)u) << 16);
}
__device__ __forceinline__ float wred(float v) {
  v += __shfl_xor(v, 1);  v += __shfl_xor(v, 2);  v += __shfl_xor(v, 4);
  v += __shfl_xor(v, 8);  v += __shfl_xor(v, 16); v += __shfl_xor(v, 32);
  return v;
}

// ---------------- K1: masked stats of pn@w1^T and pn@g1^T + counts ----------
__global__ __launch_bounds__(256) void k_stats1(
    const float* __restrict__ x, const float* __restrict__ mask,
    const float* __restrict__ w1, const float* __restrict__ g1,
    float* __restrict__ ws) {
  float acc[34];
#pragma unroll
  for (int i = 0; i < 34; i++) acc[i] = 0.f;

  int t = blockIdx.x * 256 + threadIdx.x;  // 65536 threads
#pragma unroll
  for (int pp = 0; pp < 2; pp++) {
    int s = t;               // spatial index same for both batches
    int b = pp;
    int h = s >> 10, w = s & (W_ - 1);
    const float* xb = x + (size_t)b * C_ * HW_;
    const float* mb = mask + (size_t)b * HW_;
    float xc0 = xb[s], xc1 = xb[HW_ + s], xc2 = xb[2 * HW_ + s], xc3 = xb[3 * HW_ + s];
    acc[33] += (mb[s] > 0.f) ? 1.f : 0.f;
#pragma unroll
    for (int k = 0; k < 9; k++) {
      int di = k / 3 - 1, dj = k % 3 - 1;
      int hh = h + di, ww = w + dj;
      bool inb = ((unsigned)hh < (unsigned)H_) && ((unsigned)ww < (unsigned)W_);
      int ns = inb ? hh * W_ + ww : s;   // clamped: pn==0 when !inb
      float mv = mb[ns];
      float mk = (inb && mv > 0.f) ? 1.f : 0.f;
      float pn0 = xb[ns] - xc0;
      float pn1 = xb[HW_ + ns] - xc1;
      float pn2 = xb[2 * HW_ + ns] - xc2;
      float pn3 = xb[3 * HW_ + ns] - xc3;
      acc[32] += mk;
#pragma unroll
      for (int o = 0; o < 8; o++) {
        float ta = pn0 * w1[o * 4] + pn1 * w1[o * 4 + 1] + pn2 * w1[o * 4 + 2] + pn3 * w1[o * 4 + 3];
        acc[o] += mk * ta; acc[8 + o] += mk * ta * ta;
        float tg = pn0 * g1[o * 4] + pn1 * g1[o * 4 + 1] + pn2 * g1[o * 4 + 2] + pn3 * g1[o * 4 + 3];
        acc[16 + o] += mk * tg; acc[24 + o] += mk * tg * tg;
      }
    }
  }
  __shared__ float red[4][34];
  int lane = threadIdx.x & 63, wave = threadIdx.x >> 6;
#pragma unroll
  for (int i = 0; i < 34; i++) {
    float r = wred(acc[i]);
    if (lane == 0) red[wave][i] = r;
  }
  __syncthreads();
  if (threadIdx.x < 34)
    ws[threadIdx.x * 256 + blockIdx.x] =
        red[0][threadIdx.x] + red[1][threadIdx.x] + red[2][threadIdx.x] + red[3][threadIdx.x];
}

// ---------------- K2: masked stats of relu(gbn1(pn@g1^T)) @ g2^T ------------
__global__ __launch_bounds__(256) void k_stats2(
    const float* __restrict__ x, const float* __restrict__ mask,
    const float* __restrict__ g1, const float* __restrict__ gbn1_g,
    const float* __restrict__ gbn1_b, const float* __restrict__ g2,
    float* __restrict__ ws) {
  int lane = threadIdx.x & 63, wave = threadIdx.x >> 6;
  __shared__ float stat[33];
  for (int i = 16 + wave; i < 33; i += 4) {
    const float* src = ws + i * 256;
    float v = src[lane] + src[64 + lane] + src[128 + lane] + src[192 + lane];
    v = wred(v);
    if (lane == 0) stat[i] = v;
  }
  __syncthreads();
  __shared__ float sc[8], sh[8];
  if (threadIdx.x < 8) {
    int o = threadIdx.x;
    float n = fmaxf(stat[32], 1.f);
    float mean = stat[16 + o] / n;
    float var = stat[24 + o] / n - mean * mean;
    float s = gbn1_g[o] * rsqrtf(var + EPS);
    sc[o] = s; sh[o] = gbn1_b[o] - mean * s;
  }
  __syncthreads();

  float acc[16];
#pragma unroll
  for (int i = 0; i < 16; i++) acc[i] = 0.f;

  int t = blockIdx.x * 256 + threadIdx.x;
#pragma unroll
  for (int pp = 0; pp < 2; pp++) {
    int s = t;
    int b = pp;
    int h = s >> 10, w = s & (W_ - 1);
    const float* xb = x + (size_t)b * C_ * HW_;
    const float* mb = mask + (size_t)b * HW_;
    float xc0 = xb[s], xc1 = xb[HW_ + s], xc2 = xb[2 * HW_ + s], xc3 = xb[3 * HW_ + s];
#pragma unroll
    for (int k = 0; k < 9; k++) {
      int di = k / 3 - 1, dj = k % 3 - 1;
      int hh = h + di, ww = w + dj;
      bool inb = ((unsigned)hh < (unsigned)H_) && ((unsigned)ww < (unsigned)W_);
      int ns = inb ? hh * W_ + ww : s;
      float mv = mb[ns];
      float mk = (inb && mv > 0.f) ? 1.f : 0.f;
      float pn0 = xb[ns] - xc0;
      float pn1 = xb[HW_ + ns] - xc1;
      float pn2 = xb[2 * HW_ + ns] - xc2;
      float pn3 = xb[3 * HW_ + ns] - xc3;
      float gb[8];
#pragma unroll
      for (int o = 0; o < 8; o++) {
        float tg = pn0 * g1[o * 4] + pn1 * g1[o * 4 + 1] + pn2 * g1[o * 4 + 2] + pn3 * g1[o * 4 + 3];
        gb[o] = fmaxf(sc[o] * tg + sh[o], 0.f);
      }
#pragma unroll
      for (int j = 0; j < 8; j++) {
        float t2 = 0.f;
#pragma unroll
        for (int o = 0; o < 8; o++) t2 += gb[o] * g2[j * 8 + o];
        acc[j] += mk * t2; acc[8 + j] += mk * t2 * t2;
      }
    }
  }
  __shared__ float red[4][16];
#pragma unroll
  for (int i = 0; i < 16; i++) {
    float r = wred(acc[i]);
    if (lane == 0) red[wave][i] = r;
  }
  __syncthreads();
  if (threadIdx.x < 16)
    ws[8704 + threadIdx.x * 256 + blockIdx.x] =
        red[0][threadIdx.x] + red[1][threadIdx.x] + red[2][threadIdx.x] + red[3][threadIdx.x];
}

// --------- K3: fused vec build (LDS) + MFMA GEMM + abn stats ----------------
// 1024 blocks, 128 px/block, 2 threads per pixel.
__global__ __launch_bounds__(256) void k_fused(
    const float* __restrict__ x, const float* __restrict__ mask,
    const float* __restrict__ w1, const float* __restrict__ bn1_g,
    const float* __restrict__ bn1_b, const float* __restrict__ w2,
    const float* __restrict__ b2, const float* __restrict__ g1,
    const float* __restrict__ g2, const float* __restrict__ gbn1_g,
    const float* __restrict__ gbn1_b, const float* __restrict__ gbn2_g,
    const float* __restrict__ gbn2_b, const float* __restrict__ w_agg,
    float* __restrict__ ws, unsigned short* __restrict__ out_pre) {
  __shared__ uint4 vecT[17][128];     // chunk c = bf16 K-elements [8c,8c+8): 0-7 fagg, 8-16 g
  __shared__ float stat[50];
  __shared__ float sA[8], hA[8], sG1[8], hG1[8], sG2[8], hG2[8];

  int lane = threadIdx.x & 63, wave = threadIdx.x >> 6;
  // reduce stats partials (P1: 0..33, P2: 34..49)
  for (int i = wave; i < 50; i += 4) {
    const float* src = (i < 34) ? (ws + i * 256) : (ws + 8704 + (i - 34) * 256);
    float v = src[lane] + src[64 + lane] + src[128 + lane] + src[192 + lane];
    v = wred(v);
    if (lane == 0) stat[i] = v;
  }
  __syncthreads();
  if (threadIdx.x < 24) {
    int o = threadIdx.x & 7;
    float n = fmaxf(stat[32], 1.f);
    float sum, sum2, gma, bta;
    if (threadIdx.x < 8)       { sum = stat[o];      sum2 = stat[8 + o];  gma = bn1_g[o];  bta = bn1_b[o]; }
    else if (threadIdx.x < 16) { sum = stat[16 + o]; sum2 = stat[24 + o]; gma = gbn1_g[o]; bta = gbn1_b[o]; }
    else                       { sum = stat[34 + o]; sum2 = stat[42 + o]; gma = gbn2_g[o]; bta = gbn2_b[o]; }
    float mean = sum / n, var = sum2 / n - mean * mean;
    float s = gma * rsqrtf(var + EPS);
    float sft = bta - mean * s;
    if (threadIdx.x < 8)       { sA[o] = s;  hA[o] = sft; }
    else if (threadIdx.x < 16) { sG1[o] = s; hG1[o] = sft; }
    else                       { sG2[o] = s; hG2[o] = sft; }
  }
  __syncthreads();

  int tile = (blockIdx.x & 7) * 128 + (blockIdx.x >> 3);  // XCD-contiguous over 1024
  int b = tile >> 9;
  int s0 = (tile & 511) * 128;
  int px = threadIdx.x & 127;
  int half = threadIdx.x >> 7;      // wave-uniform
  int s = s0 + px;
  int h = s >> 10, w = s & (W_ - 1);
  const float* xb = x + (size_t)b * C_ * HW_;
  const float* mb = mask + (size_t)b * HW_;
  float xc0 = xb[s], xc1 = xb[HW_ + s], xc2 = xb[2 * HW_ + s], xc3 = xb[3 * HW_ + s];
  float b2v = b2[0];

  // ---- phase 1: softmax weights (computed redundantly by both halves) ----
  float ev[9], mkv[9], ibv[9]; int nsv[9];
  float mx = -1e30f;
#pragma unroll
  for (int k = 0; k < 9; k++) {
    int di = k / 3 - 1, dj = k % 3 - 1;
    int hh = h + di, ww = w + dj;
    bool inb = ((unsigned)hh < (unsigned)H_) && ((unsigned)ww < (unsigned)W_);
    int ns = inb ? hh * W_ + ww : s;
    nsv[k] = ns;
    ibv[k] = inb ? 1.f : 0.f;
    float mv = mb[ns];
    float mk = (inb && mv > 0.f) ? 1.f : 0.f;
    mkv[k] = mk;
    float pn0 = xb[ns] - xc0;
    float pn1 = xb[HW_ + ns] - xc1;
    float pn2 = xb[2 * HW_ + ns] - xc2;
    float pn3 = xb[3 * HW_ + ns] - xc3;
    float accw = 0.f;
#pragma unroll
    for (int o = 0; o < 8; o++) {
      float ta = pn0 * w1[o * 4] + pn1 * w1[o * 4 + 1] + pn2 * w1[o * 4 + 2] + pn3 * w1[o * 4 + 3];
      accw += fmaxf(sA[o] * ta + hA[o], 0.f) * w2[o];
    }
    float wp = mk * (accw + b2v);
    ev[k] = wp;
    mx = fmaxf(mx, wp);
  }
  float den = 0.f;
#pragma unroll
  for (int k = 0; k < 9; k++) { ev[k] = __expf(ev[k] - mx); den += ev[k]; }
  float inv = 1.f / den;
  float wgv[9], wfv[9];
#pragma unroll
  for (int k = 0; k < 9; k++) {
    float wt = ev[k] * inv;
    wgv[k] = wt * mkv[k];   // g uses msel
    wfv[k] = wt * ibv[k];   // fagg uses in-bounds
  }

  // ---- phase 2a: g chunks (half 0: k 0..3, half 1: k 4..8) ----
#pragma unroll
  for (int k = 0; k < 9; k++) {
    if ((k < 4) == (half == 0)) {
      int ns = nsv[k];
      float pn0 = xb[ns] - xc0;
      float pn1 = xb[HW_ + ns] - xc1;
      float pn2 = xb[2 * HW_ + ns] - xc2;
      float pn3 = xb[3 * HW_ + ns] - xc3;
      float gb[8];
#pragma unroll
      for (int o = 0; o < 8; o++) {
        float tg = pn0 * g1[o * 4] + pn1 * g1[o * 4 + 1] + pn2 * g1[o * 4 + 2] + pn3 * g1[o * 4 + 3];
        gb[o] = fmaxf(sG1[o] * tg + hG1[o], 0.f);
      }
      float wg = wgv[k];
      float gv[8];
#pragma unroll
      for (int j = 0; j < 8; j++) {
        float t2 = 0.f;
#pragma unroll
        for (int o = 0; o < 8; o++) t2 += gb[o] * g2[j * 8 + o];
        gv[j] = wg * fmaxf(sG2[j] * t2 + hG2[j], 0.f);
      }
      uint4 pk;
      pk.x = pack2(gv[0], gv[1]); pk.y = pack2(gv[2], gv[3]);
      pk.z = pack2(gv[4], gv[5]); pk.w = pack2(gv[6], gv[7]);
      vecT[8 + k][px] = pk;
    }
  }

  // ---- phase 2b: fagg, 32 channels per half ----
  float fa[32];
#pragma unroll
  for (int c = 0; c < 32; c++) fa[c] = 0.f;
  const float* xf0 = xb + (size_t)(4 + half * 32) * HW_;
#pragma unroll
  for (int k = 0; k < 9; k++) {
    float wf = wfv[k];
    const float* xf = xf0 + nsv[k];
#pragma unroll
    for (int c = 0; c < 32; c++) fa[c] += wf * xf[c * HW_];
  }
#pragma unroll
  for (int c = 0; c < 32; c += 8) {
    uint4 pk;
    pk.x = pack2(fa[c], fa[c + 1]);     pk.y = pack2(fa[c + 2], fa[c + 3]);
    pk.z = pack2(fa[c + 4], fa[c + 5]); pk.w = pack2(fa[c + 6], fa[c + 7]);
    vecT[half * 4 + (c >> 3)][px] = pk;
  }
  __syncthreads();

  // ---- phase 3: GEMM 128x64x160, wave = (mh, nh) split ----
  int q = lane >> 4, r = lane & 15;
  int nh = wave & 1, mh = wave >> 1;

  short8 Bf[2][5];
#pragma unroll
  for (int nt = 0; nt < 2; nt++) {
    int n = (nh * 2 + nt) * 16 + r;
#pragma unroll
    for (int ks = 0; ks < 5; ks++) {
      int k0 = ks * 32 + q * 8;
      uint4 pk; pk.x = pk.y = pk.z = pk.w = 0u;
      if (k0 < 136) {
        float4 f0 = *reinterpret_cast<const float4*>(w_agg + n * 136 + k0);
        float4 f1 = *reinterpret_cast<const float4*>(w_agg + n * 136 + k0 + 4);
        pk.x = pack2(f0.x, f0.y); pk.y = pack2(f0.z, f0.w);
        pk.z = pack2(f1.x, f1.y); pk.w = pack2(f1.z, f1.w);
      }
      Bf[nt][ks] = *reinterpret_cast<short8*>(&pk);
    }
  }

  floatx4 acc[4][2];
#pragma unroll
  for (int m = 0; m < 4; m++)
#pragma unroll
    for (int nt = 0; nt < 2; nt++) acc[m][nt] = (floatx4){0.f, 0.f, 0.f, 0.f};

#pragma unroll
  for (int m = 0; m < 4; m++) {
    int pix = (mh * 4 + m) * 16 + r;
    short8 Af[5];
#pragma unroll
    for (int ks = 0; ks < 5; ks++) {
      int ch = ks * 4 + q;
      if (ch < 17)
        Af[ks] = *reinterpret_cast<const short8*>(&vecT[ch][pix]);
      else
        Af[ks] = (short8){0, 0, 0, 0, 0, 0, 0, 0};
    }
#pragma unroll
    for (int nt = 0; nt < 2; nt++)
#pragma unroll
      for (int ks = 0; ks < 5; ks++)
        acc[m][nt] = __builtin_amdgcn_mfma_f32_16x16x32_bf16(Af[ks], Bf[nt][ks], acc[m][nt], 0, 0, 0);
  }

  // stores (bf16) + masked abn stats
  float aS[2] = {0.f, 0.f}, aQ[2] = {0.f, 0.f};
#pragma unroll
  for (int m = 0; m < 4; m++) {
    int srow = s0 + (mh * 4 + m) * 16 + q * 4;
    float4 mv = *reinterpret_cast<const float4*>(mb + srow);
    float m0 = (mv.x > 0.f) ? 1.f : 0.f, m1 = (mv.y > 0.f) ? 1.f : 0.f;
    float m2 = (mv.z > 0.f) ? 1.f : 0.f, m3 = (mv.w > 0.f) ? 1.f : 0.f;
#pragma unroll
    for (int nt = 0; nt < 2; nt++) {
      int ch = (nh * 2 + nt) * 16 + r;
      float o0 = acc[m][nt][0], o1 = acc[m][nt][1], o2 = acc[m][nt][2], o3 = acc[m][nt][3];
      aS[nt] += o0 * m0 + o1 * m1 + o2 * m2 + o3 * m3;
      aQ[nt] += o0 * o0 * m0 + o1 * o1 * m1 + o2 * o2 * m2 + o3 * o3 * m3;
      uint2 pk;
      pk.x = pack2(o0, o1); pk.y = pack2(o2, o3);
      *reinterpret_cast<uint2*>(out_pre + (size_t)(b * 64 + ch) * HW_ + srow) = pk;
    }
  }

  __shared__ float rS[4][32], rQ[4][32];
#pragma unroll
  for (int nt = 0; nt < 2; nt++) {
    float v1 = aS[nt], v2 = aQ[nt];
    v1 += __shfl_xor(v1, 16); v1 += __shfl_xor(v1, 32);
    v2 += __shfl_xor(v2, 16); v2 += __shfl_xor(v2, 32);
    if (lane < 16) { rS[wave][nt * 16 + lane] = v1; rQ[wave][nt * 16 + lane] = v2; }
  }
  __syncthreads();
  if (threadIdx.x < 64) {
    int nh2 = threadIdx.x >> 5, loc = threadIdx.x & 31;
    float* AT = ws + 12800;
    atomicAdd(&AT[threadIdx.x], rS[nh2][loc] + rS[2 + nh2][loc]);
    atomicAdd(&AT[64 + threadIdx.x], rQ[nh2][loc] + rQ[2 + nh2][loc]);
  }
}

// ---------------- K4: abn apply + relu + center-mask zero -------------------
__global__ __launch_bounds__(256) void k_final(
    const unsigned short* __restrict__ out_pre, const float* __restrict__ mask,
    const float* __restrict__ abn_g, const float* __restrict__ abn_b,
    const float* __restrict__ ws, float* __restrict__ out) {
  int lane = threadIdx.x & 63, wave = threadIdx.x >> 6;
  __shared__ float l4[4];
  __shared__ float sc[64], sh[64];
  {
    float v = ws[33 * 256 + threadIdx.x];
    v = wred(v);
    if (lane == 0) l4[wave] = v;
  }
  __syncthreads();
  float n0 = fmaxf(l4[0] + l4[1] + l4[2] + l4[3], 1.f);
  if (threadIdx.x < 64) {
    int c = threadIdx.x;
    const float* AT = ws + 12800;
    float mean = AT[c] / n0;
    float var = AT[64 + c] / n0 - mean * mean;
    float s = abn_g[c] * rsqrtf(var + EPS);
    sc[c] = s; sh[c] = abn_b[c] - mean * s;
  }
  __syncthreads();

  int i8 = (blockIdx.x * 256 + threadIdx.x) * 8;
  int c = (i8 >> 16) & 63;
  int b = i8 >> 22;
  int s = i8 & (HW_ - 1);
  uint4 v = *reinterpret_cast<const uint4*>(out_pre + i8);
  float4 ma = *reinterpret_cast<const float4*>(mask + (size_t)b * HW_ + s);
  float4 mb4 = *reinterpret_cast<const float4*>(mask + (size_t)b * HW_ + s + 4);
  float scc = sc[c], shc = sh[c];
  float4 o0, o1;
  o0.x = (ma.x > 0.f) ? fmaxf(bf2f((unsigned short)(v.x & 0xffff)) * scc + shc, 0.f) : 0.f;
  o0.y = (ma.y > 0.f) ? fmaxf(bf2f((unsigned short)(v.x >> 16)) * scc + shc, 0.f) : 0.f;
  o0.z = (ma.z > 0.f) ? fmaxf(bf2f((unsigned short)(v.y & 0xffff)) * scc + shc, 0.f) : 0.f;
  o0.w = (ma.w > 0.f) ? fmaxf(bf2f((unsigned short)(v.y >> 16)) * scc + shc, 0.f) : 0.f;
  o1.x = (mb4.x > 0.f) ? fmaxf(bf2f((unsigned short)(v.z & 0xffff)) * scc + shc, 0.f) : 0.f;
  o1.y = (mb4.y > 0.f) ? fmaxf(bf2f((unsigned short)(v.z >> 16)) * scc + shc, 0.f) : 0.f;
  o1.z = (mb4.z > 0.f) ? fmaxf(bf2f((unsigned short)(v.w & 0xffff)) * scc + shc, 0.f) : 0.f;
  o1.w = (mb4.w > 0.f) ? fmaxf(bf2f((unsigned short)(v.w >> 16)) * scc + shc, 0.f) : 0.f;
  *reinterpret_cast<float4*>(out + i8) = o0;
  *reinterpret_cast<float4*>(out + i8 + 4) = o1;
}

extern "C" void kernel_launch(void* const* d_in, const int* in_sizes, int n_in,
                              void* d_out, int out_size, void* d_ws, size_t ws_size,
                              hipStream_t stream) {
  const float* x      = (const float*)d_in[0];
  const float* mask   = (const float*)d_in[1];
  const float* w1     = (const float*)d_in[2];
  const float* bn1_g  = (const float*)d_in[3];
  const float* bn1_b  = (const float*)d_in[4];
  const float* w2     = (const float*)d_in[5];
  const float* b2     = (const float*)d_in[6];
  const float* g1     = (const float*)d_in[7];
  const float* gbn1_g = (const float*)d_in[8];
  const float* gbn1_b = (const float*)d_in[9];
  const float* g2     = (const float*)d_in[10];
  const float* gbn2_g = (const float*)d_in[11];
  const float* gbn2_b = (const float*)d_in[12];
  const float* w_agg  = (const float*)d_in[13];
  const float* abn_g  = (const float*)d_in[14];
  const float* abn_b  = (const float*)d_in[15];
  float* out = (float*)d_out;

  size_t need = 53248 + (size_t)NPIX * 64 * 2;
  if (ws_size < need) return;

  float* wsf = (float*)d_ws;
  unsigned short* out_pre = (unsigned short*)((char*)d_ws + 53248);

  hipMemsetAsync((char*)d_ws + 51200, 0, 1024, stream);  // AT region
  k_stats1<<<256, 256, 0, stream>>>(x, mask, w1, g1, wsf);
  k_stats2<<<256, 256, 0, stream>>>(x, mask, g1, gbn1_g, gbn1_b, g2, wsf);
  k_fused<<<1024, 256, 0, stream>>>(x, mask, w1, bn1_g, bn1_b, w2, b2, g1, g2,
                                    gbn1_g, gbn1_b, gbn2_g, gbn2_b, w_agg,
                                    wsf, out_pre);
  k_final<<<4096, 256, 0, stream>>>(out_pre, mask, abn_g, abn_b, wsf, out);
}